// Round 7
// baseline (403.722 us; speedup 1.0000x reference)
//
#include <hip/hip_runtime.h>
#include <hip/hip_bf16.h>

typedef __hip_bfloat16 bf16;
#define SLOPE 0.2f

typedef _Float16 h2v __attribute__((ext_vector_type(2)));
typedef _Float16 h8v __attribute__((ext_vector_type(8)));
typedef __attribute__((ext_vector_type(8))) short bf16x8;
typedef __attribute__((ext_vector_type(16))) float f32x16;

__device__ __forceinline__ float b2f(bf16 v) { return __bfloat162float(v); }
__device__ __forceinline__ short f2b_raw(float x) {
    bf16 b = __float2bfloat16(x);
    return *reinterpret_cast<short*>(&b);
}
__device__ __forceinline__ short f2h_raw(float x) {
    _Float16 h = (_Float16)x;
    return *reinterpret_cast<short*>(&h);
}
__device__ __forceinline__ h2v u2h(unsigned u) {
    union { unsigned x; h2v h; } c; c.x = u; return c.h;
}

// DPP-based cross-lane add: x + x[dpp_ctrl lane]. No LDS, no lgkm wait.
template <int CTRL>
__device__ __forceinline__ float dpp_radd(float x) {
    int y = __builtin_amdgcn_update_dpp(0, __float_as_int(x), CTRL, 0xF, 0xF, false);
    return x + __int_as_float(y);
}
#define DPP_QUAD_XOR1 0xB1  // quad_perm [1,0,3,2]
#define DPP_QUAD_XOR2 0x4E  // quad_perm [2,3,0,1]
#define DPP_ROR1 0x121
#define DPP_ROR2 0x122
#define DPP_ROR4 0x124
#define DPP_ROR8 0x128

union Q16 { uint4 q[2]; unsigned u[8]; };

// ---------------- merged prep: dtype detect, weight pack (fp16), attention-coeff
// pre-scale (0.6a / 0.4a packed fp16), cnt zero, ticket zero ----
__global__ void k_prep(const void* __restrict__ x,
                       const void* __restrict__ W0, const void* __restrict__ W1,
                       const void* __restrict__ W2, const void* __restrict__ Wr2,
                       const void* __restrict__ a0, const void* __restrict__ a1,
                       const void* __restrict__ a2, short* __restrict__ W0p,
                       short* __restrict__ W1p, short* __restrict__ W2fp,
                       short* __restrict__ a60, short* __restrict__ a40,
                       short* __restrict__ a61, short* __restrict__ a41,
                       short* __restrict__ a62, short* __restrict__ a42,
                       int* __restrict__ flag,
                       int* __restrict__ cnt, int* __restrict__ ticket, int N) {
    __shared__ int sflag;
    if (threadIdx.x < 64) {
        const unsigned short* u = (const unsigned short*)x;
        int tid = threadIdx.x;
        int nice = 0;
        for (int k = tid; k < 256; k += 64) {
            unsigned int bits = ((unsigned int)u[2 * k]) << 16;
            float v = __uint_as_float(bits);
            float av = fabsf(v);
            if (v == 0.0f || (av > 1e-6f && av < 100.0f)) ++nice;
        }
        for (int off = 32; off > 0; off >>= 1) nice += __shfl_down(nice, off, 64);
        if (tid == 0) sflag = (nice >= 192) ? 0 : 1;
    }
    __syncthreads();
    int isf = sflag;
    int idx = blockIdx.x * blockDim.x + threadIdx.x;
    if (blockIdx.x == 0 && threadIdx.x == 0) { *flag = isf; *ticket = 0; }
    if (idx < N) cnt[idx] = 0;
    if (idx < 131072) {
        int t = idx & 65535;
        int j = t & 7, L = (t >> 3) & 63, kt = (t >> 9) & 15, nt = t >> 13;
        int n = nt * 32 + (L & 31);
        int k = kt * 16 + (L >> 5) * 8 + j;
        const void* src = (idx < 65536) ? W0 : W1;
        float v = isf ? ((const float*)src)[k * 256 + n] : b2f(((const bf16*)src)[k * 256 + n]);
        short* dstp = (idx < 65536) ? W0p : W1p;
        dstp[t] = f2h_raw(v);
    } else if (idx < 147456) {
        int t = idx - 131072;
        int j = t & 7, L = (t >> 3) & 63, kt = (t >> 9) & 15, nt = t >> 13;
        int n = nt * 32 + (L & 31);
        int k = kt * 16 + (L >> 5) * 8 + j;
        const void* src = (n < 32) ? W2 : Wr2;
        int nn = n & 31;
        float v = isf ? ((const float*)src)[k * 32 + nn] : b2f(((const bf16*)src)[k * 32 + nn]);
        W2fp[t] = f2h_raw(v);
    } else if (idx < 147456 + 256) {
        int t = idx - 147456;
        float v = isf ? ((const float*)a0)[t] : b2f(((const bf16*)a0)[t]);
        a60[t] = f2h_raw(0.6f * v);
        a40[t] = f2h_raw(0.4f * v);
    } else if (idx < 147456 + 512) {
        int t = idx - 147456 - 256;
        float v = isf ? ((const float*)a1)[t] : b2f(((const bf16*)a1)[t]);
        a61[t] = f2h_raw(0.6f * v);
        a41[t] = f2h_raw(0.4f * v);
    } else if (idx < 147456 + 544) {
        int t = idx - 147456 - 512;
        float v = isf ? ((const float*)a2)[t] : b2f(((const bf16*)a2)[t]);
        a62[t] = f2h_raw(0.6f * v);
        a42[t] = f2h_raw(0.4f * v);
    }
}

// ---------------- CSR build ----------------
__global__ void k_hist(const int* __restrict__ dst, int* __restrict__ cnt, int E) {
    int e = blockIdx.x * blockDim.x + threadIdx.x;
    if (e < E) atomicAdd(&cnt[dst[e]], 1);
}

__global__ void k_bsum_scan(const int* __restrict__ cnt, int* __restrict__ bsum,
                            int* __restrict__ ticket, int n, int B) {
    __shared__ int sh[256];
    __shared__ int lastFlag;
    int base = blockIdx.x * 1024 + threadIdx.x * 4;
    int s = 0;
#pragma unroll
    for (int k = 0; k < 4; ++k) { int i = base + k; if (i < n) s += cnt[i]; }
    sh[threadIdx.x] = s;
    __syncthreads();
    for (int off = 128; off > 0; off >>= 1) {
        if (threadIdx.x < off) sh[threadIdx.x] += sh[threadIdx.x + off];
        __syncthreads();
    }
    if (threadIdx.x == 0) {
        atomicExch(&bsum[blockIdx.x], sh[0]);
        __threadfence();
        int t = atomicAdd(ticket, 1);
        lastFlag = (t == B - 1) ? 1 : 0;
    }
    __syncthreads();
    if (lastFlag && threadIdx.x < 64) {
        int tid = threadIdx.x;
        int v = (tid < B) ? atomicAdd(&bsum[tid], 0) : 0;
        int xv = v;
#pragma unroll
        for (int off = 1; off < 64; off <<= 1) {
            int y = __shfl_up(xv, off, 64);
            if (tid >= off) xv += y;
        }
        if (tid < B) bsum[tid] = xv - v;
    }
}

__global__ void k_scanwrite(const int* __restrict__ cnt, const int* __restrict__ bsum,
                            int* __restrict__ rowptr, int* __restrict__ cursor, int n, int E) {
    __shared__ int sh[256];
    int base = blockIdx.x * 1024 + threadIdx.x * 4;
    int loc[4];
    int s = 0;
#pragma unroll
    for (int k = 0; k < 4; ++k) {
        int i = base + k;
        loc[k] = (i < n) ? cnt[i] : 0;
        s += loc[k];
    }
    sh[threadIdx.x] = s;
    __syncthreads();
    for (int off = 1; off < 256; off <<= 1) {
        int u = (threadIdx.x >= off) ? sh[threadIdx.x - off] : 0;
        __syncthreads();
        sh[threadIdx.x] += u;
        __syncthreads();
    }
    int run = bsum[blockIdx.x] + sh[threadIdx.x] - s;
#pragma unroll
    for (int k = 0; k < 4; ++k) {
        int i = base + k;
        if (i < n) { rowptr[i] = run; cursor[i] = run; run += loc[k]; }
    }
    if (blockIdx.x == 0 && threadIdx.x == 0) rowptr[n] = E;
}

__global__ void k_scatter(const int* __restrict__ src, const int* __restrict__ dst,
                          int* __restrict__ cursor, int* __restrict__ csr_src, int E) {
    int e = blockIdx.x * blockDim.x + threadIdx.x;
    if (e < E) {
        int p = atomicAdd(&cursor[dst[e]], 1);
        csr_src[p] = src[e];
    }
}

// ---------------- MFMA GEMM (f16): C[N,256](fp16) = A[N,256] @ W ----
template <int ADAPT>
__global__ void k_gemm_mfma(const void* __restrict__ A, const short* __restrict__ Wp,
                            short* __restrict__ C, int Nrows, const int* __restrict__ flag) {
    __shared__ short sA[64 * 264];
    int tid = threadIdx.x;
    int warp = tid >> 6;
    int lane = tid & 63;
    long blockRow = (long)blockIdx.x * 64;
    int isf32 = ADAPT ? *flag : 0;

    if (ADAPT && isf32) {
        const float* Af = (const float*)A;
#pragma unroll
        for (int it = 0; it < 16; ++it) {
            int linear = it * 256 + tid;   // float4 index; 64 per row
            int row = linear >> 6;
            int col4 = linear & 63;
            long gr = blockRow + row;
            if (gr > Nrows - 1) gr = Nrows - 1;
            float4 v = ((const float4*)(Af + gr * 256))[col4];
            short* d = &sA[row * 264 + col4 * 4];
            d[0] = f2h_raw(v.x); d[1] = f2h_raw(v.y);
            d[2] = f2h_raw(v.z); d[3] = f2h_raw(v.w);
        }
    } else if (ADAPT) {
        // bf16 external input -> fp16 internal
        const short* Ab = (const short*)A;
#pragma unroll
        for (int it = 0; it < 8; ++it) {
            int linear = it * 256 + tid;   // 16B chunk index; 32 per row
            int row = linear >> 5;
            int c8 = linear & 31;
            long gr = blockRow + row;
            if (gr > Nrows - 1) gr = Nrows - 1;
            bf16x8 v = *(const bf16x8*)(Ab + gr * 256 + c8 * 8);
            short* d = &sA[row * 264 + c8 * 8];
#pragma unroll
            for (int k = 0; k < 8; ++k) {
                unsigned bits = ((unsigned)(unsigned short)v[k]) << 16;
                d[k] = f2h_raw(__uint_as_float(bits));
            }
        }
    } else {
        // internal fp16 -> raw copy
        const short* Ab = (const short*)A;
#pragma unroll
        for (int it = 0; it < 8; ++it) {
            int linear = it * 256 + tid;
            int row = linear >> 5;
            int c8 = linear & 31;
            long gr = blockRow + row;
            if (gr > Nrows - 1) gr = Nrows - 1;
            bf16x8 v = *(const bf16x8*)(Ab + gr * 256 + c8 * 8);
            *(bf16x8*)&sA[row * 264 + c8 * 8] = v;
        }
    }
    __syncthreads();

    int wr = warp >> 1;
    int wc = warp & 1;
    long rowBase = blockRow + wr * 32;
    int colBase = wc * 128;
    int m = lane & 31;
    int g = lane >> 5;
    int smemRow = wr * 32 + m;
    f32x16 acc[4] = {};
    for (int kt = 0; kt < 16; ++kt) {
        h8v af = *(const h8v*)&sA[smemRow * 264 + kt * 16 + g * 8];
#pragma unroll
        for (int ct = 0; ct < 4; ++ct) {
            int nt = wc * 4 + ct;
            h8v bfr = *(const h8v*)(Wp + (((nt << 4) + kt) << 9) + lane * 8);
            acc[ct] = __builtin_amdgcn_mfma_f32_32x32x16_f16(af, bfr, acc[ct], 0, 0, 0);
        }
    }
#pragma unroll
    for (int ct = 0; ct < 4; ++ct) {
#pragma unroll
        for (int i = 0; i < 16; ++i) {
            long row = rowBase + (i & 3) + 8 * (i >> 2) + 4 * g;
            if (row < Nrows)
                C[row * 256 + colBase + ct * 32 + m] = f2h_raw(acc[ct][i]);
        }
    }
}

// C[N,64](fp16) = A[N,256](fp16) @ combined final weights (fragment-packed)
__global__ void k_gemm_mfma64(const short* __restrict__ A, const short* __restrict__ Wp,
                              short* __restrict__ C, int Nrows) {
    int warp = threadIdx.x >> 6;
    int lane = threadIdx.x & 63;
    long rowBase = (long)blockIdx.x * 128 + warp * 32;
    int m = lane & 31;
    int g = lane >> 5;
    long r = rowBase + m;
    if (r >= Nrows) r = Nrows - 1;
    const short* Arow = A + r * 256 + g * 8;
    f32x16 acc[2] = {};
    for (int kt = 0; kt < 16; ++kt) {
        h8v af = *(const h8v*)(Arow + kt * 16);
#pragma unroll
        for (int ct = 0; ct < 2; ++ct) {
            h8v bfr = *(const h8v*)(Wp + (((ct << 4) + kt) << 9) + lane * 8);
            acc[ct] = __builtin_amdgcn_mfma_f32_32x32x16_f16(af, bfr, acc[ct], 0, 0, 0);
        }
    }
#pragma unroll
    for (int ct = 0; ct < 2; ++ct) {
#pragma unroll
        for (int i = 0; i < 16; ++i) {
            long row = rowBase + (i & 3) + 8 * (i >> 2) + 4 * g;
            if (row < Nrows)
                C[row * 64 + ct * 32 + m] = f2h_raw(acc[ct][i]);
        }
    }
}

// ---------------- Fused GATv2 layer: 1024-thread blocks (launch-rate fix) +
// index-ahead gather pipeline + precomputed 0.6a/0.4a (zero preamble VALU). ----
__global__ void __launch_bounds__(1024)
k_gat_fused(const uint4* __restrict__ f, const short* __restrict__ a6,
            const short* __restrict__ a4,
            const int* __restrict__ rowptr, const int* __restrict__ csr_src,
            const uint4* __restrict__ res, uint4* __restrict__ out,
            int N, int mode) {
    int n = (blockIdx.x * blockDim.x + threadIdx.x) >> 6;
    int lane = threadIdx.x & 63;
    if (n >= N) return;
    int j = lane >> 4, l = lane & 15;

    Q16 fdq, aq6, aq4;
    fdq.q[0] = f[(long)n * 32 + 2 * l];
    fdq.q[1] = f[(long)n * 32 + 2 * l + 1];
    aq6.q[0] = ((const uint4*)a6)[2 * l];
    aq6.q[1] = ((const uint4*)a6)[2 * l + 1];
    aq4.q[0] = ((const uint4*)a4)[2 * l];
    aq4.q[1] = ((const uint4*)a4)[2 * l + 1];
    h2v a6h[8], a4h[8];
#pragma unroll
    for (int i = 0; i < 8; ++i) {
        a6h[i] = u2h(aq6.u[i]);
        a4h[i] = u2h(aq4.u[i]);
    }

    int p0 = rowptr[n], p1 = rowptr[n + 1];
    int iters = (p1 - p0 + 3) >> 2;
    float z = 0.f;
    float accx[8] = {}, accy[8] = {};

    int p = p0 + j;
    int pc = p1 - 1;
    Q16 A0, A1, B0, B1;
    // iter-0 gathers
    {
        int s0 = csr_src[min(p, pc)];
        A0.q[0] = f[(long)s0 * 32 + 2 * l];
        A0.q[1] = f[(long)s0 * 32 + 2 * l + 1];
        int s1 = csr_src[min(p + 4, pc)];
        A1.q[0] = f[(long)s1 * 32 + 2 * l];
        A1.q[1] = f[(long)s1 * 32 + 2 * l + 1];
    }
    // indices for iter-1 gathers, loaded a full iteration early
    int t0i = csr_src[min(p + 8, pc)];
    int t1i = csr_src[min(p + 12, pc)];

    for (int i = 0; i < iters; i += 2) {
        // issue next-iter gathers immediately (addresses already resolved)
        B0.q[0] = f[(long)t0i * 32 + 2 * l];
        B0.q[1] = f[(long)t0i * 32 + 2 * l + 1];
        B1.q[0] = f[(long)t1i * 32 + 2 * l];
        B1.q[1] = f[(long)t1i * 32 + 2 * l + 1];
        // prefetch indices for the iteration after next
        int u0i = csr_src[min(p + 16, pc)];
        int u1i = csr_src[min(p + 20, pc)];

#pragma unroll
        for (int half = 0; half < 2; ++half) {
            if (half == 1 && i + 1 >= iters) break;
            const Q16& cur = half ? A1 : A0;
            int pp = p + half * 4;
            float ta0 = 0.f, ta1 = 0.f, ta2 = 0.f, ta3 = 0.f;
#pragma unroll
            for (int k = 0; k < 8; ++k) {
                unsigned uu;
                asm("v_pk_add_f16 %0, %1, %2" : "=v"(uu) : "v"(cur.u[k]), "v"(fdq.u[k]));
                unsigned ua = uu & 0x7fff7fffu;
                if ((k & 1) == 0) {
                    ta0 = __builtin_amdgcn_fdot2(u2h(uu), a6h[k], ta0, false);
                    ta1 = __builtin_amdgcn_fdot2(u2h(ua), a4h[k], ta1, false);
                } else {
                    ta2 = __builtin_amdgcn_fdot2(u2h(uu), a6h[k], ta2, false);
                    ta3 = __builtin_amdgcn_fdot2(u2h(ua), a4h[k], ta3, false);
                }
            }
            float t = (ta0 + ta1) + (ta2 + ta3);
            t = dpp_radd<DPP_QUAD_XOR1>(t);
            t = dpp_radd<DPP_QUAD_XOR2>(t);
            float wgt = (pp < p1) ? __expf(t) : 0.f;
            z += wgt;
#pragma unroll
            for (int k = 0; k < 8; ++k) {
                asm("v_fma_mix_f32 %0, %1, %2, %0 op_sel_hi:[1,0,0]"
                    : "+v"(accx[k]) : "v"(cur.u[k]), "v"(wgt));
                asm("v_fma_mix_f32 %0, %1, %2, %0 op_sel:[1,0,0] op_sel_hi:[1,0,0]"
                    : "+v"(accy[k]) : "v"(cur.u[k]), "v"(wgt));
            }
        }
        A0 = B0;
        A1 = B1;
        t0i = u0i;
        t1i = u1i;
        p += 8;
    }
    z += __shfl_xor(z, 16);
    z += __shfl_xor(z, 32);
#pragma unroll
    for (int k = 0; k < 8; ++k) {
        accx[k] += __shfl_xor(accx[k], 16);
        accx[k] += __shfl_xor(accx[k], 32);
        accy[k] += __shfl_xor(accy[k], 16);
        accy[k] += __shfl_xor(accy[k], 32);
    }
    if (j < 2) {
        float invz = 1.f / z;
        float o[8];
#pragma unroll
        for (int k = 0; k < 4; ++k) {
            int kk = j * 4 + k;
            o[2 * k]     = accx[kk] * invz;
            o[2 * k + 1] = accy[kk] * invz;
        }
        if (mode == 1) {
            uint4 rq = res[(long)n * 32 + 2 * l + j];
            const unsigned* ru = (const unsigned*)&rq;
#pragma unroll
            for (int k = 0; k < 4; ++k) {
                h2v rh = u2h(ru[k]);
                o[2 * k]     += (float)rh.x;
                o[2 * k + 1] += (float)rh.y;
            }
        }
        union { uint4 q; short s[8]; } ob;
#pragma unroll
        for (int k = 0; k < 8; ++k) {
            float v = o[k] > 0.f ? o[k] : (__expf(o[k]) - 1.f);
            ob.s[k] = f2h_raw(v);
        }
        out[(long)n * 32 + 2 * l + j] = ob.q;
    }
}

// ---------------- Fused final layer: 1024-thread blocks + index-ahead pipeline ----------
__global__ void __launch_bounds__(1024)
k_gat_fused_fin(const unsigned* __restrict__ fr2u, const short* __restrict__ a62,
                const short* __restrict__ a42,
                const int* __restrict__ rowptr, const int* __restrict__ csr_src,
                void* __restrict__ outraw, int N, const int* __restrict__ flag) {
    int n = (blockIdx.x * blockDim.x + threadIdx.x) >> 6;
    int lane = threadIdx.x & 63;
    if (n >= N) return;
    int j = lane >> 4, l = lane & 15;

    unsigned fdu = fr2u[(long)n * 32 + l];
    h2v a6h = u2h(((const unsigned*)a62)[l]);
    h2v a4h = u2h(((const unsigned*)a42)[l]);

    int p0 = rowptr[n], p1 = rowptr[n + 1];
    int iters = (p1 - p0 + 3) >> 2;
    float z = 0.f;
    float accx = 0.f, accy = 0.f;

    int p = p0 + j;
    int pc = p1 - 1;
    unsigned A0, A1, B0, B1;
    A0 = fr2u[(long)csr_src[min(p, pc)] * 32 + l];
    A1 = fr2u[(long)csr_src[min(p + 4, pc)] * 32 + l];
    int t0i = csr_src[min(p + 8, pc)];
    int t1i = csr_src[min(p + 12, pc)];
    for (int i = 0; i < iters; i += 2) {
        B0 = fr2u[(long)t0i * 32 + l];
        B1 = fr2u[(long)t1i * 32 + l];
        int u0i = csr_src[min(p + 16, pc)];
        int u1i = csr_src[min(p + 20, pc)];
#pragma unroll
        for (int half = 0; half < 2; ++half) {
            if (half == 1 && i + 1 >= iters) break;
            unsigned cu = half ? A1 : A0;
            int pp = p + half * 4;
            unsigned uu;
            asm("v_pk_add_f16 %0, %1, %2" : "=v"(uu) : "v"(cu), "v"(fdu));
            unsigned ua = uu & 0x7fff7fffu;
            float t = __builtin_amdgcn_fdot2(u2h(uu), a6h, 0.f, false);
            t = __builtin_amdgcn_fdot2(u2h(ua), a4h, t, false);
            // rotate-allreduce over the 16-lane row (ring sums)
            t = dpp_radd<DPP_ROR1>(t);
            t = dpp_radd<DPP_ROR2>(t);
            t = dpp_radd<DPP_ROR4>(t);
            t = dpp_radd<DPP_ROR8>(t);
            float wgt = (pp < p1) ? __expf(t) : 0.f;
            z += wgt;
            asm("v_fma_mix_f32 %0, %1, %2, %0 op_sel_hi:[1,0,0]"
                : "+v"(accx) : "v"(cu), "v"(wgt));
            asm("v_fma_mix_f32 %0, %1, %2, %0 op_sel:[1,0,0] op_sel_hi:[1,0,0]"
                : "+v"(accy) : "v"(cu), "v"(wgt));
        }
        A0 = B0;
        A1 = B1;
        t0i = u0i;
        t1i = u1i;
        p += 8;
    }
    z += __shfl_xor(z, 16);
    z += __shfl_xor(z, 32);
    accx += __shfl_xor(accx, 16);
    accx += __shfl_xor(accx, 32);
    accy += __shfl_xor(accy, 16);
    accy += __shfl_xor(accy, 32);
    if (j == 0) {
        unsigned ru = fr2u[(long)n * 32 + 16 + l];
        h2v rh = u2h(ru);
        float invz = 1.f / z;
        float o0 = accx * invz + (float)rh.x;
        float o1 = accy * invz + (float)rh.y;
        if (*flag) {
            float2 ov = {o0, o1};
            ((float2*)outraw)[(long)n * 16 + l] = ov;
        } else {
            unsigned ob = ((unsigned)(unsigned short)f2b_raw(o0)) |
                          (((unsigned)(unsigned short)f2b_raw(o1)) << 16);
            ((unsigned*)outraw)[(long)n * 16 + l] = ob;
        }
    }
}

extern "C" void kernel_launch(void* const* d_in, const int* in_sizes, int n_in,
                              void* d_out, int out_size, void* d_ws, size_t ws_size,
                              hipStream_t stream) {
    const int N = in_sizes[0] / 256;
    const int E = in_sizes[1];

    const void* x   = d_in[0];
    const int*  src = (const int*)d_in[1];
    const int*  dst = (const int*)d_in[2];

    // ---- workspace carve ----
    char* w = (char*)d_ws;
    auto alloc = [&](size_t bytes) -> char* {
        char* p = w;
        w += (bytes + 15) & ~(size_t)15;
        return p;
    };
    short* buf0 = (short*)alloc((size_t)N * 256 * 2);  // hB
    short* buf1 = (short*)alloc((size_t)N * 256 * 2);  // hA
    short* buf2 = (short*)alloc((size_t)N * 256 * 2);  // fB / fr2
    int* csr_src = (int*)alloc((size_t)E * 4);
    int* rowptr  = (int*)alloc((size_t)(N + 1) * 4);
    int* cursor  = (int*)alloc((size_t)N * 4);
    int* cnt     = (int*)alloc((size_t)N * 4);
    int* bsum    = (int*)alloc((size_t)1024 * 4);
    short* W0p  = (short*)alloc((size_t)65536 * 2);
    short* W1p  = (short*)alloc((size_t)65536 * 2);
    short* W2fp = (short*)alloc((size_t)64 * 256 * 2);
    short* a60  = (short*)alloc((size_t)256 * 2);
    short* a40  = (short*)alloc((size_t)256 * 2);
    short* a61  = (short*)alloc((size_t)256 * 2);
    short* a41  = (short*)alloc((size_t)256 * 2);
    short* a62  = (short*)alloc((size_t)32 * 2);
    short* a42  = (short*)alloc((size_t)32 * 2);
    int*  flag = (int*)alloc(16);
    int*  ticket = (int*)alloc(16);

    short* hA  = buf1;
    short* fB  = buf2;
    short* hB  = buf0;
    short* fr2 = buf2;

    // ---- merged prep (flag + weights + coeff pre-scale + cnt zero + ticket zero) ----
    int prepN = 147456 + 544;
    if (prepN < N) prepN = N;
    k_prep<<<(prepN + 255) / 256, 256, 0, stream>>>(
        x, d_in[3], d_in[5], d_in[7], d_in[9], d_in[4], d_in[6], d_in[8],
        W0p, W1p, W2fp, a60, a40, a61, a41, a62, a42, flag, cnt, ticket, N);

    // ---- CSR build ----
    const int B = (N + 1023) / 1024;
    k_hist<<<(E + 255) / 256, 256, 0, stream>>>(dst, cnt, E);
    k_bsum_scan<<<B, 256, 0, stream>>>(cnt, bsum, ticket, N, B);
    k_scanwrite<<<B, 256, 0, stream>>>(cnt, bsum, rowptr, cursor, N, E);
    k_scatter<<<(E + 255) / 256, 256, 0, stream>>>(src, dst, cursor, csr_src, E);

    // 1024-thread blocks: 16 nodes/block -> 4x fewer launches (launch-rate fix)
    const int ngrid16 = (int)(((long)N * 64 + 1023) / 1024);

    // ---- layer 0 (x read directly, converted to fp16 during LDS staging) ----
    k_gemm_mfma<1><<<(N + 63) / 64, 256, 0, stream>>>(x, W0p, fB, N, flag);
    k_gat_fused<<<ngrid16, 1024, 0, stream>>>((const uint4*)fB, a60, a40, rowptr, csr_src,
                                              nullptr, (uint4*)hA, N, 0);
    // ---- layer 1 (hA is ALWAYS fp16 -> non-adaptive) ----
    k_gemm_mfma<0><<<(N + 63) / 64, 256, 0, stream>>>(hA, W1p, fB, N, flag);
    k_gat_fused<<<ngrid16, 1024, 0, stream>>>((const uint4*)fB, a61, a41, rowptr, csr_src,
                                              (const uint4*)hA, (uint4*)hB, N, 1);
    // ---- final layer ----
    k_gemm_mfma64<<<(N + 127) / 128, 256, 0, stream>>>(hB, W2fp, fr2, N);
    k_gat_fused_fin<<<ngrid16, 1024, 0, stream>>>((const unsigned*)fr2, a62, a42,
                                                  rowptr, csr_src, d_out, N, flag);
}

// Round 8
// 373.618 us; speedup vs baseline: 1.0806x; 1.0806x over previous
//
#include <hip/hip_runtime.h>
#include <hip/hip_bf16.h>

typedef __hip_bfloat16 bf16;
#define SLOPE 0.2f

typedef _Float16 h2v __attribute__((ext_vector_type(2)));
typedef _Float16 h8v __attribute__((ext_vector_type(8)));
typedef __attribute__((ext_vector_type(8))) short bf16x8;
typedef __attribute__((ext_vector_type(16))) float f32x16;

__device__ __forceinline__ float b2f(bf16 v) { return __bfloat162float(v); }
__device__ __forceinline__ short f2b_raw(float x) {
    bf16 b = __float2bfloat16(x);
    return *reinterpret_cast<short*>(&b);
}
__device__ __forceinline__ short f2h_raw(float x) {
    _Float16 h = (_Float16)x;
    return *reinterpret_cast<short*>(&h);
}
__device__ __forceinline__ h2v u2h(unsigned u) {
    union { unsigned x; h2v h; } c; c.x = u; return c.h;
}
__device__ __forceinline__ unsigned h2u(h2v h) {
    union { h2v h; unsigned x; } c; c.h = h; return c.x;
}
__device__ __forceinline__ unsigned pkadd_u(unsigned a, unsigned b) {
    unsigned r;
    asm("v_pk_add_f16 %0, %1, %2" : "=v"(r) : "v"(a), "v"(b));
    return r;
}

// DPP-based cross-lane add: x + x[dpp_ctrl lane]. No LDS, no lgkm wait.
template <int CTRL>
__device__ __forceinline__ float dpp_radd(float x) {
    int y = __builtin_amdgcn_update_dpp(0, __float_as_int(x), CTRL, 0xF, 0xF, false);
    return x + __int_as_float(y);
}
#define DPP_QUAD_XOR1 0xB1  // quad_perm [1,0,3,2]
#define DPP_QUAD_XOR2 0x4E  // quad_perm [2,3,0,1]
#define DPP_ROR1 0x121
#define DPP_ROR2 0x122
#define DPP_ROR4 0x124
#define DPP_ROR8 0x128

union Q16 { uint4 q[2]; unsigned u[8]; };

// ---------------- merged prep: dtype detect, weight pack (fp16), attention-coeff
// pre-scale (0.6a / 0.4a packed fp16), cnt zero, ticket zero ----
__global__ void k_prep(const void* __restrict__ x,
                       const void* __restrict__ W0, const void* __restrict__ W1,
                       const void* __restrict__ W2, const void* __restrict__ Wr2,
                       const void* __restrict__ a0, const void* __restrict__ a1,
                       const void* __restrict__ a2, short* __restrict__ W0p,
                       short* __restrict__ W1p, short* __restrict__ W2fp,
                       short* __restrict__ a60, short* __restrict__ a40,
                       short* __restrict__ a61, short* __restrict__ a41,
                       short* __restrict__ a62, short* __restrict__ a42,
                       int* __restrict__ flag,
                       int* __restrict__ cnt, int* __restrict__ ticket, int N) {
    __shared__ int sflag;
    if (threadIdx.x < 64) {
        const unsigned short* u = (const unsigned short*)x;
        int tid = threadIdx.x;
        int nice = 0;
        for (int k = tid; k < 256; k += 64) {
            unsigned int bits = ((unsigned int)u[2 * k]) << 16;
            float v = __uint_as_float(bits);
            float av = fabsf(v);
            if (v == 0.0f || (av > 1e-6f && av < 100.0f)) ++nice;
        }
        for (int off = 32; off > 0; off >>= 1) nice += __shfl_down(nice, off, 64);
        if (tid == 0) sflag = (nice >= 192) ? 0 : 1;
    }
    __syncthreads();
    int isf = sflag;
    int idx = blockIdx.x * blockDim.x + threadIdx.x;
    if (blockIdx.x == 0 && threadIdx.x == 0) { *flag = isf; *ticket = 0; }
    if (idx < N) cnt[idx] = 0;
    if (idx < 131072) {
        int t = idx & 65535;
        int j = t & 7, L = (t >> 3) & 63, kt = (t >> 9) & 15, nt = t >> 13;
        int n = nt * 32 + (L & 31);
        int k = kt * 16 + (L >> 5) * 8 + j;
        const void* src = (idx < 65536) ? W0 : W1;
        float v = isf ? ((const float*)src)[k * 256 + n] : b2f(((const bf16*)src)[k * 256 + n]);
        short* dstp = (idx < 65536) ? W0p : W1p;
        dstp[t] = f2h_raw(v);
    } else if (idx < 147456) {
        int t = idx - 131072;
        int j = t & 7, L = (t >> 3) & 63, kt = (t >> 9) & 15, nt = t >> 13;
        int n = nt * 32 + (L & 31);
        int k = kt * 16 + (L >> 5) * 8 + j;
        const void* src = (n < 32) ? W2 : Wr2;
        int nn = n & 31;
        float v = isf ? ((const float*)src)[k * 32 + nn] : b2f(((const bf16*)src)[k * 32 + nn]);
        W2fp[t] = f2h_raw(v);
    } else if (idx < 147456 + 256) {
        int t = idx - 147456;
        float v = isf ? ((const float*)a0)[t] : b2f(((const bf16*)a0)[t]);
        a60[t] = f2h_raw(0.6f * v);
        a40[t] = f2h_raw(0.4f * v);
    } else if (idx < 147456 + 512) {
        int t = idx - 147456 - 256;
        float v = isf ? ((const float*)a1)[t] : b2f(((const bf16*)a1)[t]);
        a61[t] = f2h_raw(0.6f * v);
        a41[t] = f2h_raw(0.4f * v);
    } else if (idx < 147456 + 544) {
        int t = idx - 147456 - 512;
        float v = isf ? ((const float*)a2)[t] : b2f(((const bf16*)a2)[t]);
        a62[t] = f2h_raw(0.6f * v);
        a42[t] = f2h_raw(0.4f * v);
    }
}

// ---------------- CSR build ----------------
__global__ void k_hist(const int* __restrict__ dst, int* __restrict__ cnt, int E) {
    int e = blockIdx.x * blockDim.x + threadIdx.x;
    if (e < E) atomicAdd(&cnt[dst[e]], 1);
}

__global__ void k_bsum_scan(const int* __restrict__ cnt, int* __restrict__ bsum,
                            int* __restrict__ ticket, int n, int B) {
    __shared__ int sh[256];
    __shared__ int lastFlag;
    int base = blockIdx.x * 1024 + threadIdx.x * 4;
    int s = 0;
#pragma unroll
    for (int k = 0; k < 4; ++k) { int i = base + k; if (i < n) s += cnt[i]; }
    sh[threadIdx.x] = s;
    __syncthreads();
    for (int off = 128; off > 0; off >>= 1) {
        if (threadIdx.x < off) sh[threadIdx.x] += sh[threadIdx.x + off];
        __syncthreads();
    }
    if (threadIdx.x == 0) {
        atomicExch(&bsum[blockIdx.x], sh[0]);
        __threadfence();
        int t = atomicAdd(ticket, 1);
        lastFlag = (t == B - 1) ? 1 : 0;
    }
    __syncthreads();
    if (lastFlag && threadIdx.x < 64) {
        int tid = threadIdx.x;
        int v = (tid < B) ? atomicAdd(&bsum[tid], 0) : 0;
        int xv = v;
#pragma unroll
        for (int off = 1; off < 64; off <<= 1) {
            int y = __shfl_up(xv, off, 64);
            if (tid >= off) xv += y;
        }
        if (tid < B) bsum[tid] = xv - v;
    }
}

__global__ void k_scanwrite(const int* __restrict__ cnt, const int* __restrict__ bsum,
                            int* __restrict__ rowptr, int* __restrict__ cursor, int n, int E) {
    __shared__ int sh[256];
    int base = blockIdx.x * 1024 + threadIdx.x * 4;
    int loc[4];
    int s = 0;
#pragma unroll
    for (int k = 0; k < 4; ++k) {
        int i = base + k;
        loc[k] = (i < n) ? cnt[i] : 0;
        s += loc[k];
    }
    sh[threadIdx.x] = s;
    __syncthreads();
    for (int off = 1; off < 256; off <<= 1) {
        int u = (threadIdx.x >= off) ? sh[threadIdx.x - off] : 0;
        __syncthreads();
        sh[threadIdx.x] += u;
        __syncthreads();
    }
    int run = bsum[blockIdx.x] + sh[threadIdx.x] - s;
#pragma unroll
    for (int k = 0; k < 4; ++k) {
        int i = base + k;
        if (i < n) { rowptr[i] = run; cursor[i] = run; run += loc[k]; }
    }
    if (blockIdx.x == 0 && threadIdx.x == 0) rowptr[n] = E;
}

__global__ void k_scatter(const int* __restrict__ src, const int* __restrict__ dst,
                          int* __restrict__ cursor, int* __restrict__ csr_src, int E) {
    int e = blockIdx.x * blockDim.x + threadIdx.x;
    if (e < E) {
        int p = atomicAdd(&cursor[dst[e]], 1);
        csr_src[p] = src[e];
    }
}

// ---------------- MFMA GEMM (f16): C[N,256](fp16) = A[N,256] @ W ----
template <int ADAPT>
__global__ void k_gemm_mfma(const void* __restrict__ A, const short* __restrict__ Wp,
                            short* __restrict__ C, int Nrows, const int* __restrict__ flag) {
    __shared__ short sA[64 * 264];
    int tid = threadIdx.x;
    int warp = tid >> 6;
    int lane = tid & 63;
    long blockRow = (long)blockIdx.x * 64;
    int isf32 = ADAPT ? *flag : 0;

    if (ADAPT && isf32) {
        const float* Af = (const float*)A;
#pragma unroll
        for (int it = 0; it < 16; ++it) {
            int linear = it * 256 + tid;   // float4 index; 64 per row
            int row = linear >> 6;
            int col4 = linear & 63;
            long gr = blockRow + row;
            if (gr > Nrows - 1) gr = Nrows - 1;
            float4 v = ((const float4*)(Af + gr * 256))[col4];
            short* d = &sA[row * 264 + col4 * 4];
            d[0] = f2h_raw(v.x); d[1] = f2h_raw(v.y);
            d[2] = f2h_raw(v.z); d[3] = f2h_raw(v.w);
        }
    } else if (ADAPT) {
        // bf16 external input -> fp16 internal
        const short* Ab = (const short*)A;
#pragma unroll
        for (int it = 0; it < 8; ++it) {
            int linear = it * 256 + tid;   // 16B chunk index; 32 per row
            int row = linear >> 5;
            int c8 = linear & 31;
            long gr = blockRow + row;
            if (gr > Nrows - 1) gr = Nrows - 1;
            bf16x8 v = *(const bf16x8*)(Ab + gr * 256 + c8 * 8);
            short* d = &sA[row * 264 + c8 * 8];
#pragma unroll
            for (int k = 0; k < 8; ++k) {
                unsigned bits = ((unsigned)(unsigned short)v[k]) << 16;
                d[k] = f2h_raw(__uint_as_float(bits));
            }
        }
    } else {
        // internal fp16 -> raw copy
        const short* Ab = (const short*)A;
#pragma unroll
        for (int it = 0; it < 8; ++it) {
            int linear = it * 256 + tid;
            int row = linear >> 5;
            int c8 = linear & 31;
            long gr = blockRow + row;
            if (gr > Nrows - 1) gr = Nrows - 1;
            bf16x8 v = *(const bf16x8*)(Ab + gr * 256 + c8 * 8);
            *(bf16x8*)&sA[row * 264 + c8 * 8] = v;
        }
    }
    __syncthreads();

    int wr = warp >> 1;
    int wc = warp & 1;
    long rowBase = blockRow + wr * 32;
    int colBase = wc * 128;
    int m = lane & 31;
    int g = lane >> 5;
    int smemRow = wr * 32 + m;
    f32x16 acc[4] = {};
    for (int kt = 0; kt < 16; ++kt) {
        h8v af = *(const h8v*)&sA[smemRow * 264 + kt * 16 + g * 8];
#pragma unroll
        for (int ct = 0; ct < 4; ++ct) {
            int nt = wc * 4 + ct;
            h8v bfr = *(const h8v*)(Wp + (((nt << 4) + kt) << 9) + lane * 8);
            acc[ct] = __builtin_amdgcn_mfma_f32_32x32x16_f16(af, bfr, acc[ct], 0, 0, 0);
        }
    }
#pragma unroll
    for (int ct = 0; ct < 4; ++ct) {
#pragma unroll
        for (int i = 0; i < 16; ++i) {
            long row = rowBase + (i & 3) + 8 * (i >> 2) + 4 * g;
            if (row < Nrows)
                C[row * 256 + colBase + ct * 32 + m] = f2h_raw(acc[ct][i]);
        }
    }
}

// C[N,64](fp16) = A[N,256](fp16) @ combined final weights (fragment-packed)
__global__ void k_gemm_mfma64(const short* __restrict__ A, const short* __restrict__ Wp,
                              short* __restrict__ C, int Nrows) {
    int warp = threadIdx.x >> 6;
    int lane = threadIdx.x & 63;
    long rowBase = (long)blockIdx.x * 128 + warp * 32;
    int m = lane & 31;
    int g = lane >> 5;
    long r = rowBase + m;
    if (r >= Nrows) r = Nrows - 1;
    const short* Arow = A + r * 256 + g * 8;
    f32x16 acc[2] = {};
    for (int kt = 0; kt < 16; ++kt) {
        h8v af = *(const h8v*)(Arow + kt * 16);
#pragma unroll
        for (int ct = 0; ct < 2; ++ct) {
            h8v bfr = *(const h8v*)(Wp + (((ct << 4) + kt) << 9) + lane * 8);
            acc[ct] = __builtin_amdgcn_mfma_f32_32x32x16_f16(af, bfr, acc[ct], 0, 0, 0);
        }
    }
#pragma unroll
    for (int ct = 0; ct < 2; ++ct) {
#pragma unroll
        for (int i = 0; i < 16; ++i) {
            long row = rowBase + (i & 3) + 8 * (i >> 2) + 4 * g;
            if (row < Nrows)
                C[row * 64 + ct * 32 + m] = f2h_raw(acc[ct][i]);
        }
    }
}

// ---------------- Fused GATv2 layer: 256-thd blocks (proven), index-ahead pipeline,
// precomputed 0.6a/0.4a, packed-f16 message accumulation (8 pk_fma vs 16 fma_mix). ----
__global__ void k_gat_fused(const uint4* __restrict__ f, const short* __restrict__ a6,
                            const short* __restrict__ a4,
                            const int* __restrict__ rowptr, const int* __restrict__ csr_src,
                            const uint4* __restrict__ res, uint4* __restrict__ out,
                            int N, int mode) {
    int n = (blockIdx.x * blockDim.x + threadIdx.x) >> 6;
    int lane = threadIdx.x & 63;
    if (n >= N) return;
    int j = lane >> 4, l = lane & 15;

    Q16 fdq, aq6, aq4;
    fdq.q[0] = f[(long)n * 32 + 2 * l];
    fdq.q[1] = f[(long)n * 32 + 2 * l + 1];
    aq6.q[0] = ((const uint4*)a6)[2 * l];
    aq6.q[1] = ((const uint4*)a6)[2 * l + 1];
    aq4.q[0] = ((const uint4*)a4)[2 * l];
    aq4.q[1] = ((const uint4*)a4)[2 * l + 1];
    h2v a6h[8], a4h[8];
#pragma unroll
    for (int i = 0; i < 8; ++i) {
        a6h[i] = u2h(aq6.u[i]);
        a4h[i] = u2h(aq4.u[i]);
    }

    int p0 = rowptr[n], p1 = rowptr[n + 1];
    int iters = (p1 - p0 + 3) >> 2;
    float z = 0.f;
    unsigned accp[8] = {};   // packed f16 pair accumulators (msg)

    int p = p0 + j;
    int pc = p1 - 1;
    Q16 A0, A1, B0, B1;
    // iter-0 gathers
    {
        int s0 = csr_src[min(p, pc)];
        A0.q[0] = f[(long)s0 * 32 + 2 * l];
        A0.q[1] = f[(long)s0 * 32 + 2 * l + 1];
        int s1 = csr_src[min(p + 4, pc)];
        A1.q[0] = f[(long)s1 * 32 + 2 * l];
        A1.q[1] = f[(long)s1 * 32 + 2 * l + 1];
    }
    // indices for iter-1 gathers, loaded a full iteration early
    int t0i = csr_src[min(p + 8, pc)];
    int t1i = csr_src[min(p + 12, pc)];

    for (int i = 0; i < iters; i += 2) {
        // issue next-iter gathers immediately (addresses already resolved)
        B0.q[0] = f[(long)t0i * 32 + 2 * l];
        B0.q[1] = f[(long)t0i * 32 + 2 * l + 1];
        B1.q[0] = f[(long)t1i * 32 + 2 * l];
        B1.q[1] = f[(long)t1i * 32 + 2 * l + 1];
        // prefetch indices for the iteration after next
        int u0i = csr_src[min(p + 16, pc)];
        int u1i = csr_src[min(p + 20, pc)];

#pragma unroll
        for (int half = 0; half < 2; ++half) {
            if (half == 1 && i + 1 >= iters) break;
            const Q16& cur = half ? A1 : A0;
            int pp = p + half * 4;
            float ta0 = 0.f, ta1 = 0.f, ta2 = 0.f, ta3 = 0.f;
#pragma unroll
            for (int k = 0; k < 8; ++k) {
                unsigned uu;
                asm("v_pk_add_f16 %0, %1, %2" : "=v"(uu) : "v"(cur.u[k]), "v"(fdq.u[k]));
                unsigned ua = uu & 0x7fff7fffu;
                if ((k & 1) == 0) {
                    ta0 = __builtin_amdgcn_fdot2(u2h(uu), a6h[k], ta0, false);
                    ta1 = __builtin_amdgcn_fdot2(u2h(ua), a4h[k], ta1, false);
                } else {
                    ta2 = __builtin_amdgcn_fdot2(u2h(uu), a6h[k], ta2, false);
                    ta3 = __builtin_amdgcn_fdot2(u2h(ua), a4h[k], ta3, false);
                }
            }
            float t = (ta0 + ta1) + (ta2 + ta3);
            t = dpp_radd<DPP_QUAD_XOR1>(t);
            t = dpp_radd<DPP_QUAD_XOR2>(t);
            float wgt = (pp < p1) ? __expf(t) : 0.f;
            z += wgt;
            // replicate wgt into a packed f16 pair
            h2v w2;
            _Float16 wh = (_Float16)wgt;
            w2.x = wh; w2.y = wh;
            unsigned w2u = h2u(w2);
#pragma unroll
            for (int k = 0; k < 8; ++k) {
                asm("v_pk_fma_f16 %0, %1, %2, %0"
                    : "+v"(accp[k]) : "v"(cur.u[k]), "v"(w2u));
            }
        }
        A0 = B0;
        A1 = B1;
        t0i = u0i;
        t1i = u1i;
        p += 8;
    }
    z += __shfl_xor(z, 16);
    z += __shfl_xor(z, 32);
#pragma unroll
    for (int k = 0; k < 8; ++k) {
        accp[k] = pkadd_u(accp[k], __shfl_xor(accp[k], 16));
        accp[k] = pkadd_u(accp[k], __shfl_xor(accp[k], 32));
    }
    if (j < 2) {
        float invz = 1.f / z;
        float o[8];
#pragma unroll
        for (int k = 0; k < 4; ++k) {
            int kk = j * 4 + k;
            h2v ah = u2h(accp[kk]);
            o[2 * k]     = (float)ah.x * invz;
            o[2 * k + 1] = (float)ah.y * invz;
        }
        if (mode == 1) {
            uint4 rq = res[(long)n * 32 + 2 * l + j];
            const unsigned* ru = (const unsigned*)&rq;
#pragma unroll
            for (int k = 0; k < 4; ++k) {
                h2v rh = u2h(ru[k]);
                o[2 * k]     += (float)rh.x;
                o[2 * k + 1] += (float)rh.y;
            }
        }
        union { uint4 q; short s[8]; } ob;
#pragma unroll
        for (int k = 0; k < 8; ++k) {
            float v = o[k] > 0.f ? o[k] : (__expf(o[k]) - 1.f);
            ob.s[k] = f2h_raw(v);
        }
        out[(long)n * 32 + 2 * l + j] = ob.q;
    }
}

// ---------------- Fused final layer: 256-thd blocks + index-ahead pipeline ----------
__global__ void k_gat_fused_fin(const unsigned* __restrict__ fr2u, const short* __restrict__ a62,
                                const short* __restrict__ a42,
                                const int* __restrict__ rowptr, const int* __restrict__ csr_src,
                                void* __restrict__ outraw, int N, const int* __restrict__ flag) {
    int n = (blockIdx.x * blockDim.x + threadIdx.x) >> 6;
    int lane = threadIdx.x & 63;
    if (n >= N) return;
    int j = lane >> 4, l = lane & 15;

    unsigned fdu = fr2u[(long)n * 32 + l];
    h2v a6h = u2h(((const unsigned*)a62)[l]);
    h2v a4h = u2h(((const unsigned*)a42)[l]);

    int p0 = rowptr[n], p1 = rowptr[n + 1];
    int iters = (p1 - p0 + 3) >> 2;
    float z = 0.f;
    float accx = 0.f, accy = 0.f;

    int p = p0 + j;
    int pc = p1 - 1;
    unsigned A0, A1, B0, B1;
    A0 = fr2u[(long)csr_src[min(p, pc)] * 32 + l];
    A1 = fr2u[(long)csr_src[min(p + 4, pc)] * 32 + l];
    int t0i = csr_src[min(p + 8, pc)];
    int t1i = csr_src[min(p + 12, pc)];
    for (int i = 0; i < iters; i += 2) {
        B0 = fr2u[(long)t0i * 32 + l];
        B1 = fr2u[(long)t1i * 32 + l];
        int u0i = csr_src[min(p + 16, pc)];
        int u1i = csr_src[min(p + 20, pc)];
#pragma unroll
        for (int half = 0; half < 2; ++half) {
            if (half == 1 && i + 1 >= iters) break;
            unsigned cu = half ? A1 : A0;
            int pp = p + half * 4;
            unsigned uu;
            asm("v_pk_add_f16 %0, %1, %2" : "=v"(uu) : "v"(cu), "v"(fdu));
            unsigned ua = uu & 0x7fff7fffu;
            float t = __builtin_amdgcn_fdot2(u2h(uu), a6h, 0.f, false);
            t = __builtin_amdgcn_fdot2(u2h(ua), a4h, t, false);
            // rotate-allreduce over the 16-lane row (ring sums)
            t = dpp_radd<DPP_ROR1>(t);
            t = dpp_radd<DPP_ROR2>(t);
            t = dpp_radd<DPP_ROR4>(t);
            t = dpp_radd<DPP_ROR8>(t);
            float wgt = (pp < p1) ? __expf(t) : 0.f;
            z += wgt;
            asm("v_fma_mix_f32 %0, %1, %2, %0 op_sel_hi:[1,0,0]"
                : "+v"(accx) : "v"(cu), "v"(wgt));
            asm("v_fma_mix_f32 %0, %1, %2, %0 op_sel:[1,0,0] op_sel_hi:[1,0,0]"
                : "+v"(accy) : "v"(cu), "v"(wgt));
        }
        A0 = B0;
        A1 = B1;
        t0i = u0i;
        t1i = u1i;
        p += 8;
    }
    z += __shfl_xor(z, 16);
    z += __shfl_xor(z, 32);
    accx += __shfl_xor(accx, 16);
    accx += __shfl_xor(accx, 32);
    accy += __shfl_xor(accy, 16);
    accy += __shfl_xor(accy, 32);
    if (j == 0) {
        unsigned ru = fr2u[(long)n * 32 + 16 + l];
        h2v rh = u2h(ru);
        float invz = 1.f / z;
        float o0 = accx * invz + (float)rh.x;
        float o1 = accy * invz + (float)rh.y;
        if (*flag) {
            float2 ov = {o0, o1};
            ((float2*)outraw)[(long)n * 16 + l] = ov;
        } else {
            unsigned ob = ((unsigned)(unsigned short)f2b_raw(o0)) |
                          (((unsigned)(unsigned short)f2b_raw(o1)) << 16);
            ((unsigned*)outraw)[(long)n * 16 + l] = ob;
        }
    }
}

extern "C" void kernel_launch(void* const* d_in, const int* in_sizes, int n_in,
                              void* d_out, int out_size, void* d_ws, size_t ws_size,
                              hipStream_t stream) {
    const int N = in_sizes[0] / 256;
    const int E = in_sizes[1];

    const void* x   = d_in[0];
    const int*  src = (const int*)d_in[1];
    const int*  dst = (const int*)d_in[2];

    // ---- workspace carve ----
    char* w = (char*)d_ws;
    auto alloc = [&](size_t bytes) -> char* {
        char* p = w;
        w += (bytes + 15) & ~(size_t)15;
        return p;
    };
    short* buf0 = (short*)alloc((size_t)N * 256 * 2);  // hB
    short* buf1 = (short*)alloc((size_t)N * 256 * 2);  // hA
    short* buf2 = (short*)alloc((size_t)N * 256 * 2);  // fB / fr2
    int* csr_src = (int*)alloc((size_t)E * 4);
    int* rowptr  = (int*)alloc((size_t)(N + 1) * 4);
    int* cursor  = (int*)alloc((size_t)N * 4);
    int* cnt     = (int*)alloc((size_t)N * 4);
    int* bsum    = (int*)alloc((size_t)1024 * 4);
    short* W0p  = (short*)alloc((size_t)65536 * 2);
    short* W1p  = (short*)alloc((size_t)65536 * 2);
    short* W2fp = (short*)alloc((size_t)64 * 256 * 2);
    short* a60  = (short*)alloc((size_t)256 * 2);
    short* a40  = (short*)alloc((size_t)256 * 2);
    short* a61  = (short*)alloc((size_t)256 * 2);
    short* a41  = (short*)alloc((size_t)256 * 2);
    short* a62  = (short*)alloc((size_t)32 * 2);
    short* a42  = (short*)alloc((size_t)32 * 2);
    int*  flag = (int*)alloc(16);
    int*  ticket = (int*)alloc(16);

    short* hA  = buf1;
    short* fB  = buf2;
    short* hB  = buf0;
    short* fr2 = buf2;

    // ---- merged prep (flag + weights + coeff pre-scale + cnt zero + ticket zero) ----
    int prepN = 147456 + 544;
    if (prepN < N) prepN = N;
    k_prep<<<(prepN + 255) / 256, 256, 0, stream>>>(
        x, d_in[3], d_in[5], d_in[7], d_in[9], d_in[4], d_in[6], d_in[8],
        W0p, W1p, W2fp, a60, a40, a61, a41, a62, a42, flag, cnt, ticket, N);

    // ---- CSR build ----
    const int B = (N + 1023) / 1024;
    k_hist<<<(E + 255) / 256, 256, 0, stream>>>(dst, cnt, E);
    k_bsum_scan<<<B, 256, 0, stream>>>(cnt, bsum, ticket, N, B);
    k_scanwrite<<<B, 256, 0, stream>>>(cnt, bsum, rowptr, cursor, N, E);
    k_scatter<<<(E + 255) / 256, 256, 0, stream>>>(src, dst, cursor, csr_src, E);

    const int ngrid4 = (int)(((long)N * 64 + 255) / 256);

    // ---- layer 0 (x read directly, converted to fp16 during LDS staging) ----
    k_gemm_mfma<1><<<(N + 63) / 64, 256, 0, stream>>>(x, W0p, fB, N, flag);
    k_gat_fused<<<ngrid4, 256, 0, stream>>>((const uint4*)fB, a60, a40, rowptr, csr_src,
                                            nullptr, (uint4*)hA, N, 0);
    // ---- layer 1 (hA is ALWAYS fp16 -> non-adaptive) ----
    k_gemm_mfma<0><<<(N + 63) / 64, 256, 0, stream>>>(hA, W1p, fB, N, flag);
    k_gat_fused<<<ngrid4, 256, 0, stream>>>((const uint4*)fB, a61, a41, rowptr, csr_src,
                                            (const uint4*)hA, (uint4*)hB, N, 1);
    // ---- final layer ----
    k_gemm_mfma64<<<(N + 127) / 128, 256, 0, stream>>>(hB, W2fp, fr2, N);
    k_gat_fused_fin<<<ngrid4, 256, 0, stream>>>((const unsigned*)fr2, a62, a42,
                                                rowptr, csr_src, d_out, N, flag);
}